// Round 1
// baseline (621.876 us; speedup 1.0000x reference)
//
#include <hip/hip_runtime.h>
#include <math.h>

// Problem constants (fixed by the reference file)
#define NN 100000
#define EE 1600000
#define DIM 128
#define ROWS_PER_BLOCK 64
#define NB 98            // ceil(NN / 1024) scan blocks

// ---------------------------------------------------------------------------
// Kernel 0: Wt[k*128+c] = W[c*128+k] * mask[k]   (mask folded into W, transposed
// so the GEMM reads Wt rows coalesced as float4). 16K elements, trivial.
// ---------------------------------------------------------------------------
__global__ __launch_bounds__(256) void k_wt(const float* __restrict__ W,
                                            const float* __restrict__ mask,
                                            float* __restrict__ Wt) {
    int o = blockIdx.x * 256 + threadIdx.x;
    if (o < DIM * DIM) {
        int k = o >> 7, c = o & 127;
        Wt[o] = W[c * DIM + k] * mask[k];
    }
}

// ---------------------------------------------------------------------------
// Kernel 1: h = feat @ Wt  (fp32 vector GEMM), fused s = leaky_relu(h @ attn).
// Block = 256 threads handles 64 rows. Thread (tc=t&31, tr=t>>5) computes
// 8 rows x 4 cols. No LDS: within a wave, the 32 lanes sharing tr request the
// same feat float4 (HW broadcast, feat read once per block); Wt is 64 KB and
// L1/L2-resident. 4096 FMAs/thread.
// ---------------------------------------------------------------------------
__global__ __launch_bounds__(256) void k_gemm(const float* __restrict__ feat,
                                              const float* __restrict__ Wt,
                                              const float* __restrict__ attn,
                                              float* __restrict__ h,
                                              float* __restrict__ s) {
    const int t  = threadIdx.x;
    const int tc = t & 31;          // col group: cols 4*tc .. 4*tc+3
    const int tr = t >> 5;          // row group: 8 rows
    const int row_base = blockIdx.x * ROWS_PER_BLOCK + tr * 8;

    const float4* featV = (const float4*)feat;
    const float4* WtV   = (const float4*)Wt;

    float4 acc[8];
#pragma unroll
    for (int j = 0; j < 8; ++j) acc[j] = make_float4(0.f, 0.f, 0.f, 0.f);
    bool ok[8];
#pragma unroll
    for (int j = 0; j < 8; ++j) ok[j] = (row_base + j) < NN;

    for (int k4 = 0; k4 < 32; ++k4) {
        float4 w0 = WtV[(4 * k4 + 0) * 32 + tc];
        float4 w1 = WtV[(4 * k4 + 1) * 32 + tc];
        float4 w2 = WtV[(4 * k4 + 2) * 32 + tc];
        float4 w3 = WtV[(4 * k4 + 3) * 32 + tc];
#pragma unroll
        for (int j = 0; j < 8; ++j) {
            float4 fv = ok[j] ? featV[(size_t)(row_base + j) * 32 + k4]
                              : make_float4(0.f, 0.f, 0.f, 0.f);
            acc[j].x += fv.x * w0.x + fv.y * w1.x + fv.z * w2.x + fv.w * w3.x;
            acc[j].y += fv.x * w0.y + fv.y * w1.y + fv.z * w2.y + fv.w * w3.y;
            acc[j].z += fv.x * w0.z + fv.y * w1.z + fv.z * w2.z + fv.w * w3.z;
            acc[j].w += fv.x * w0.w + fv.y * w1.w + fv.z * w2.w + fv.w * w3.w;
        }
    }

    float4 av = ((const float4*)attn)[tc];
#pragma unroll
    for (int j = 0; j < 8; ++j) {
        int row = row_base + j;
        if (ok[j]) ((float4*)h)[(size_t)row * 32 + tc] = acc[j];
        // s[row] = leaky_relu(sum_c h[row][c] * attn[c]) — reduce over the
        // 32 lanes (same tr) that hold this row's 128 cols.
        float p = acc[j].x * av.x + acc[j].y * av.y + acc[j].z * av.z + acc[j].w * av.w;
        p += __shfl_xor(p, 1, 64);
        p += __shfl_xor(p, 2, 64);
        p += __shfl_xor(p, 4, 64);
        p += __shfl_xor(p, 8, 64);
        p += __shfl_xor(p, 16, 64);
        if (tc == 0 && ok[j]) s[row] = (p > 0.f) ? p : 0.01f * p;
    }
}

// ---------------------------------------------------------------------------
// Kernel 2: histogram of dst -> deg[]
// ---------------------------------------------------------------------------
__global__ __launch_bounds__(256) void k_hist(const int* __restrict__ dst,
                                              int* __restrict__ deg) {
    for (int e = blockIdx.x * blockDim.x + threadIdx.x; e < EE;
         e += gridDim.x * blockDim.x)
        atomicAdd(&deg[dst[e]], 1);
}

// ---------------------------------------------------------------------------
// Kernels 3-5: exclusive scan of deg -> offs (CSR row pointers).
// A: per-block (1024 elems) scan, B: scan of 98 block sums, C: add + copy to cursor.
// ---------------------------------------------------------------------------
__global__ __launch_bounds__(256) void k_scan_a(const int* __restrict__ deg,
                                                int* __restrict__ excl,
                                                int* __restrict__ bsum) {
    __shared__ int wsum[4];
    __shared__ int woff[4];
    const int t = threadIdx.x, b = blockIdx.x;
    const int base = b * 1024 + t * 4;
    int v0 = (base + 0) < NN ? deg[base + 0] : 0;
    int v1 = (base + 1) < NN ? deg[base + 1] : 0;
    int v2 = (base + 2) < NN ? deg[base + 2] : 0;
    int v3 = (base + 3) < NN ? deg[base + 3] : 0;
    int tsum = v0 + v1 + v2 + v3;

    const int lane = t & 63, w = t >> 6;
    int incl = tsum;
#pragma unroll
    for (int d = 1; d < 64; d <<= 1) {
        int n = __shfl_up(incl, d, 64);
        if (lane >= d) incl += n;
    }
    if (lane == 63) wsum[w] = incl;
    __syncthreads();
    if (t == 0) {
        int run = 0;
#pragma unroll
        for (int i = 0; i < 4; ++i) { woff[i] = run; run += wsum[i]; }
        bsum[b] = run;
    }
    __syncthreads();
    int texcl = incl - tsum + woff[w];
    if (base + 0 < NN) excl[base + 0] = texcl;
    if (base + 1 < NN) excl[base + 1] = texcl + v0;
    if (base + 2 < NN) excl[base + 2] = texcl + v0 + v1;
    if (base + 3 < NN) excl[base + 3] = texcl + v0 + v1 + v2;
}

__global__ void k_scan_b(const int* __restrict__ bsum, int* __restrict__ boff) {
    if (threadIdx.x == 0 && blockIdx.x == 0) {
        int run = 0;
        for (int i = 0; i < NB; ++i) { boff[i] = run; run += bsum[i]; }
    }
}

__global__ __launch_bounds__(256) void k_scan_c(int* __restrict__ offs,
                                                const int* __restrict__ boff,
                                                int* __restrict__ cursor) {
    int i = blockIdx.x * 256 + threadIdx.x;
    if (i < NN) {
        int v = offs[i] + boff[i >> 10];
        offs[i] = v;
        cursor[i] = v;
    }
    if (i == 0) offs[NN] = EE;
}

// ---------------------------------------------------------------------------
// Kernel 6: scatter edges into CSR order (store src index per slot).
// ---------------------------------------------------------------------------
__global__ __launch_bounds__(256) void k_scatter(const int* __restrict__ src,
                                                 const int* __restrict__ dst,
                                                 int* __restrict__ cursor,
                                                 int* __restrict__ ssrc) {
    for (int e = blockIdx.x * blockDim.x + threadIdx.x; e < EE;
         e += gridDim.x * blockDim.x) {
        int d = dst[e];
        int pos = atomicAdd(&cursor[d], 1);
        ssrc[pos] = src[e];
    }
}

// ---------------------------------------------------------------------------
// Kernel 7: one wave per dst node — single-pass online softmax + weighted
// aggregation. Lane holds cols [2*lane, 2*lane+1]; each edge gathers one
// contiguous 512B row of h (wave-coalesced), L3-resident.
// ---------------------------------------------------------------------------
__global__ __launch_bounds__(256) void k_agg(const float* __restrict__ h,
                                             const float* __restrict__ s,
                                             const int* __restrict__ offs,
                                             const int* __restrict__ ssrc,
                                             float* __restrict__ out) {
    const int wid  = blockIdx.x * 4 + (threadIdx.x >> 6);  // node id
    const int lane = threadIdx.x & 63;
    if (wid >= NN) return;
    const int beg = offs[wid], end = offs[wid + 1];

    const float2* h2 = (const float2*)h;
    float m = -INFINITY, l = 0.f;
    float2 acc = make_float2(0.f, 0.f);

    for (int p = beg; p < end; ++p) {
        int sidx = ssrc[p];           // same addr across wave -> broadcast
        float x = s[sidx];            // same addr across wave -> broadcast
        float nm = fmaxf(m, x);
        float scale = __expf(m - nm); // first iter: exp(-inf) = 0
        float wgt   = __expf(x - nm);
        float2 hv = h2[(size_t)sidx * 64 + lane];
        acc.x = acc.x * scale + hv.x * wgt;
        acc.y = acc.y * scale + hv.y * wgt;
        l = l * scale + wgt;
        m = nm;
    }

    float2 res;
    if (l > 0.f) {
        res.x = fmaxf(acc.x / l, 0.f);
        res.y = fmaxf(acc.y / l, 0.f);
    } else {
        res = make_float2(0.f, 0.f);  // empty segment -> relu(0) = 0
    }
    ((float2*)out)[(size_t)wid * 64 + lane] = res;
}

// ---------------------------------------------------------------------------
extern "C" void kernel_launch(void* const* d_in, const int* in_sizes, int n_in,
                              void* d_out, int out_size, void* d_ws, size_t ws_size,
                              hipStream_t stream) {
    const float* feat = (const float*)d_in[0];
    const float* mask = (const float*)d_in[1];
    const float* W    = (const float*)d_in[2];
    const float* attn = (const float*)d_in[3];
    const int*   src  = (const int*)d_in[4];
    const int*   dst  = (const int*)d_in[5];
    float* out = (float*)d_out;

    // Workspace carve-up (~59.3 MB total)
    char* ws = (char*)d_ws;
    size_t off = 0;
    auto alloc = [&](size_t bytes) -> void* {
        void* p = ws + off;
        off = (off + bytes + 511) & ~(size_t)511;
        return p;
    };
    float* h      = (float*)alloc((size_t)NN * DIM * 4);  // 51.2 MB
    float* sv     = (float*)alloc((size_t)NN * 4);
    float* Wt     = (float*)alloc((size_t)DIM * DIM * 4);
    int*   deg    = (int*)alloc((size_t)NN * 4);
    int*   offs   = (int*)alloc((size_t)(NN + 1) * 4);
    int*   cursor = (int*)alloc((size_t)NN * 4);
    int*   bsum   = (int*)alloc((size_t)NB * 4);
    int*   boff   = (int*)alloc((size_t)NB * 4);
    int*   ssrc   = (int*)alloc((size_t)EE * 4);          // 6.4 MB

    hipMemsetAsync(deg, 0, (size_t)NN * 4, stream);

    k_wt<<<(DIM * DIM + 255) / 256, 256, 0, stream>>>(W, mask, Wt);
    k_gemm<<<(NN + ROWS_PER_BLOCK - 1) / ROWS_PER_BLOCK, 256, 0, stream>>>(
        feat, Wt, attn, h, sv);
    k_hist<<<1024, 256, 0, stream>>>(dst, deg);
    k_scan_a<<<NB, 256, 0, stream>>>(deg, offs, bsum);
    k_scan_b<<<1, 64, 0, stream>>>(bsum, boff);
    k_scan_c<<<(NN + 255) / 256, 256, 0, stream>>>(offs, boff, cursor);
    k_scatter<<<1024, 256, 0, stream>>>(src, dst, cursor, ssrc);
    k_agg<<<(NN + 3) / 4, 256, 0, stream>>>(h, sv, offs, ssrc, out);
}

// Round 2
// 472.361 us; speedup vs baseline: 1.3165x; 1.3165x over previous
//
#include <hip/hip_runtime.h>
#include <hip/hip_fp16.h>
#include <math.h>

// Problem constants (fixed by the reference file)
#define NN 100000
#define EE 1600000
#define DIM 128
#define ROWS_PER_BLOCK 64
#define NB 98            // ceil(NN / 1024) scan blocks

// ---------------------------------------------------------------------------
// Kernel 0: Wt[k*128+c] = W[c*128+k] * mask[k]
// ---------------------------------------------------------------------------
__global__ __launch_bounds__(256) void k_wt(const float* __restrict__ W,
                                            const float* __restrict__ mask,
                                            float* __restrict__ Wt) {
    int o = blockIdx.x * 256 + threadIdx.x;
    if (o < DIM * DIM) {
        int k = o >> 7, c = o & 127;
        Wt[o] = W[c * DIM + k] * mask[k];
    }
}

// ---------------------------------------------------------------------------
// Kernel 1: h = feat @ Wt (fp32 vector GEMM), fused s = leaky_relu(h @ attn).
// Epilogue stores h as fp16 (hh) only — k_agg's gather reads fp16 rows
// (256 B/row instead of 512 B), and the fp32 h array is never materialized.
// ---------------------------------------------------------------------------
__global__ __launch_bounds__(256) void k_gemm(const float* __restrict__ feat,
                                              const float* __restrict__ Wt,
                                              const float* __restrict__ attn,
                                              __half* __restrict__ hh,
                                              float* __restrict__ s) {
    const int t  = threadIdx.x;
    const int tc = t & 31;          // col group: cols 4*tc .. 4*tc+3
    const int tr = t >> 5;          // row group: 8 rows
    const int row_base = blockIdx.x * ROWS_PER_BLOCK + tr * 8;

    const float4* featV = (const float4*)feat;
    const float4* WtV   = (const float4*)Wt;

    float4 acc[8];
#pragma unroll
    for (int j = 0; j < 8; ++j) acc[j] = make_float4(0.f, 0.f, 0.f, 0.f);
    bool ok[8];
#pragma unroll
    for (int j = 0; j < 8; ++j) ok[j] = (row_base + j) < NN;

    for (int k4 = 0; k4 < 32; ++k4) {
        float4 w0 = WtV[(4 * k4 + 0) * 32 + tc];
        float4 w1 = WtV[(4 * k4 + 1) * 32 + tc];
        float4 w2 = WtV[(4 * k4 + 2) * 32 + tc];
        float4 w3 = WtV[(4 * k4 + 3) * 32 + tc];
#pragma unroll
        for (int j = 0; j < 8; ++j) {
            float4 fv = ok[j] ? featV[(size_t)(row_base + j) * 32 + k4]
                              : make_float4(0.f, 0.f, 0.f, 0.f);
            acc[j].x += fv.x * w0.x + fv.y * w1.x + fv.z * w2.x + fv.w * w3.x;
            acc[j].y += fv.x * w0.y + fv.y * w1.y + fv.z * w2.y + fv.w * w3.y;
            acc[j].z += fv.x * w0.z + fv.y * w1.z + fv.z * w2.z + fv.w * w3.z;
            acc[j].w += fv.x * w0.w + fv.y * w1.w + fv.z * w2.w + fv.w * w3.w;
        }
    }

    float4 av = ((const float4*)attn)[tc];
#pragma unroll
    for (int j = 0; j < 8; ++j) {
        int row = row_base + j;
        if (ok[j]) {
            __half2 lo = __floats2half2_rn(acc[j].x, acc[j].y);
            __half2 hi = __floats2half2_rn(acc[j].z, acc[j].w);
            uint2 pk;
            pk.x = *(const unsigned int*)&lo;
            pk.y = *(const unsigned int*)&hi;
            ((uint2*)hh)[(size_t)row * 32 + tc] = pk;   // 8B/lane, coalesced
        }
        float p = acc[j].x * av.x + acc[j].y * av.y + acc[j].z * av.z + acc[j].w * av.w;
        p += __shfl_xor(p, 1, 64);
        p += __shfl_xor(p, 2, 64);
        p += __shfl_xor(p, 4, 64);
        p += __shfl_xor(p, 8, 64);
        p += __shfl_xor(p, 16, 64);
        if (tc == 0 && ok[j]) s[row] = (p > 0.f) ? p : 0.01f * p;
    }
}

// ---------------------------------------------------------------------------
// Kernel 2: histogram of dst -> deg[]
// ---------------------------------------------------------------------------
__global__ __launch_bounds__(256) void k_hist(const int* __restrict__ dst,
                                              int* __restrict__ deg) {
    for (int e = blockIdx.x * blockDim.x + threadIdx.x; e < EE;
         e += gridDim.x * blockDim.x)
        atomicAdd(&deg[dst[e]], 1);
}

// ---------------------------------------------------------------------------
// Kernels 3-5: exclusive scan of deg -> offs (CSR row pointers).
// ---------------------------------------------------------------------------
__global__ __launch_bounds__(256) void k_scan_a(const int* __restrict__ deg,
                                                int* __restrict__ excl,
                                                int* __restrict__ bsum) {
    __shared__ int wsum[4];
    __shared__ int woff[4];
    const int t = threadIdx.x, b = blockIdx.x;
    const int base = b * 1024 + t * 4;
    int v0 = (base + 0) < NN ? deg[base + 0] : 0;
    int v1 = (base + 1) < NN ? deg[base + 1] : 0;
    int v2 = (base + 2) < NN ? deg[base + 2] : 0;
    int v3 = (base + 3) < NN ? deg[base + 3] : 0;
    int tsum = v0 + v1 + v2 + v3;

    const int lane = t & 63, w = t >> 6;
    int incl = tsum;
#pragma unroll
    for (int d = 1; d < 64; d <<= 1) {
        int n = __shfl_up(incl, d, 64);
        if (lane >= d) incl += n;
    }
    if (lane == 63) wsum[w] = incl;
    __syncthreads();
    if (t == 0) {
        int run = 0;
#pragma unroll
        for (int i = 0; i < 4; ++i) { woff[i] = run; run += wsum[i]; }
        bsum[b] = run;
    }
    __syncthreads();
    int texcl = incl - tsum + woff[w];
    if (base + 0 < NN) excl[base + 0] = texcl;
    if (base + 1 < NN) excl[base + 1] = texcl + v0;
    if (base + 2 < NN) excl[base + 2] = texcl + v0 + v1;
    if (base + 3 < NN) excl[base + 3] = texcl + v0 + v1 + v2;
}

// One wave, shuffle scan (was: 1 thread doing 98 serial dependent loads)
__global__ __launch_bounds__(64) void k_scan_b(const int* __restrict__ bsum,
                                               int* __restrict__ boff) {
    const int lane = threadIdx.x & 63;
    const int i0 = 2 * lane, i1 = 2 * lane + 1;
    int v0 = (i0 < NB) ? bsum[i0] : 0;
    int v1 = (i1 < NB) ? bsum[i1] : 0;
    int t = v0 + v1;
    int incl = t;
#pragma unroll
    for (int d = 1; d < 64; d <<= 1) {
        int n = __shfl_up(incl, d, 64);
        if (lane >= d) incl += n;
    }
    int excl = incl - t;
    if (i0 < NB) boff[i0] = excl;
    if (i1 < NB) boff[i1] = excl + v0;
}

__global__ __launch_bounds__(256) void k_scan_c(int* __restrict__ offs,
                                                const int* __restrict__ boff,
                                                int* __restrict__ cursor) {
    int i = blockIdx.x * 256 + threadIdx.x;
    if (i < NN) {
        int v = offs[i] + boff[i >> 10];
        offs[i] = v;
        cursor[i] = v;
    }
    if (i == 0) offs[NN] = EE;
}

// ---------------------------------------------------------------------------
// Kernel 6: scatter edges into CSR order; pack (src_idx, s[src]) as int2 so
// k_agg does one broadcast 8B load per edge instead of two dependent gathers.
// ---------------------------------------------------------------------------
__global__ __launch_bounds__(256) void k_scatter(const int* __restrict__ src,
                                                 const int* __restrict__ dst,
                                                 const float* __restrict__ s,
                                                 int* __restrict__ cursor,
                                                 int2* __restrict__ pack) {
    for (int e = blockIdx.x * blockDim.x + threadIdx.x; e < EE;
         e += gridDim.x * blockDim.x) {
        int d  = dst[e];
        int si = src[e];
        float x = s[si];
        int pos = atomicAdd(&cursor[d], 1);
        pack[pos] = make_int2(si, __float_as_int(x));
    }
}

// ---------------------------------------------------------------------------
// Kernel 7: one wave per dst node. Phase 1: lane-parallel max of s over the
// node's edges (no serial chain). Phase 2: independent-iteration weighted
// accumulation, unroll x4 (4 fp16 row-gathers in flight), denominator
// accumulated alongside (identical in every lane). Lane holds 2 cols (half2).
// ---------------------------------------------------------------------------
__global__ __launch_bounds__(256) void k_agg(const __half* __restrict__ hh,
                                             const int* __restrict__ offs,
                                             const int2* __restrict__ pack,
                                             float* __restrict__ out) {
    const int wid  = blockIdx.x * 4 + (threadIdx.x >> 6);
    const int lane = threadIdx.x & 63;
    if (wid >= NN) return;
    const int beg = offs[wid], end = offs[wid + 1];

    // Phase 1: max over edges, lane-strided, then wave max-reduce.
    float m = -INFINITY;
    for (int p = beg + lane; p < end; p += 64)
        m = fmaxf(m, __int_as_float(pack[p].y));
#pragma unroll
    for (int d = 1; d < 64; d <<= 1)
        m = fmaxf(m, __shfl_xor(m, d, 64));

    // Phase 2: weighted accumulation, 4 independent gathers in flight.
    const __half2* h2 = (const __half2*)hh;
    float l = 0.f;
    float2 a0 = make_float2(0.f, 0.f), a1 = make_float2(0.f, 0.f);
    float2 a2 = make_float2(0.f, 0.f), a3 = make_float2(0.f, 0.f);
    int p = beg;
    for (; p + 3 < end; p += 4) {
        int2 e0 = pack[p], e1 = pack[p + 1], e2 = pack[p + 2], e3 = pack[p + 3];
        float w0 = __expf(__int_as_float(e0.y) - m);
        float w1 = __expf(__int_as_float(e1.y) - m);
        float w2 = __expf(__int_as_float(e2.y) - m);
        float w3 = __expf(__int_as_float(e3.y) - m);
        __half2 v0 = h2[(size_t)e0.x * 64 + lane];
        __half2 v1 = h2[(size_t)e1.x * 64 + lane];
        __half2 v2 = h2[(size_t)e2.x * 64 + lane];
        __half2 v3 = h2[(size_t)e3.x * 64 + lane];
        float2 f0 = __half22float2(v0), f1 = __half22float2(v1);
        float2 f2 = __half22float2(v2), f3 = __half22float2(v3);
        a0.x = fmaf(f0.x, w0, a0.x); a0.y = fmaf(f0.y, w0, a0.y);
        a1.x = fmaf(f1.x, w1, a1.x); a1.y = fmaf(f1.y, w1, a1.y);
        a2.x = fmaf(f2.x, w2, a2.x); a2.y = fmaf(f2.y, w2, a2.y);
        a3.x = fmaf(f3.x, w3, a3.x); a3.y = fmaf(f3.y, w3, a3.y);
        l += (w0 + w1) + (w2 + w3);
    }
    for (; p < end; ++p) {
        int2 e0 = pack[p];
        float w0 = __expf(__int_as_float(e0.y) - m);
        float2 f0 = __half22float2(h2[(size_t)e0.x * 64 + lane]);
        a0.x = fmaf(f0.x, w0, a0.x); a0.y = fmaf(f0.y, w0, a0.y);
        l += w0;
    }

    float inv = (l > 0.f) ? (1.0f / l) : 0.f;
    float rx = fmaxf((a0.x + a1.x + a2.x + a3.x) * inv, 0.f);
    float ry = fmaxf((a0.y + a1.y + a2.y + a3.y) * inv, 0.f);
    ((float2*)out)[(size_t)wid * 64 + lane] = make_float2(rx, ry);
}

// ---------------------------------------------------------------------------
extern "C" void kernel_launch(void* const* d_in, const int* in_sizes, int n_in,
                              void* d_out, int out_size, void* d_ws, size_t ws_size,
                              hipStream_t stream) {
    const float* feat = (const float*)d_in[0];
    const float* mask = (const float*)d_in[1];
    const float* W    = (const float*)d_in[2];
    const float* attn = (const float*)d_in[3];
    const int*   src  = (const int*)d_in[4];
    const int*   dst  = (const int*)d_in[5];
    float* out = (float*)d_out;

    // Workspace carve-up (~40 MB total)
    char* ws = (char*)d_ws;
    size_t off = 0;
    auto alloc = [&](size_t bytes) -> void* {
        void* p = ws + off;
        off = (off + bytes + 511) & ~(size_t)511;
        return p;
    };
    __half* hh    = (__half*)alloc((size_t)NN * DIM * 2); // 25.6 MB
    float*  sv    = (float*)alloc((size_t)NN * 4);
    float*  Wt    = (float*)alloc((size_t)DIM * DIM * 4);
    int*    deg   = (int*)alloc((size_t)NN * 4);
    int*    offs  = (int*)alloc((size_t)(NN + 1) * 4);
    int*    cursor= (int*)alloc((size_t)NN * 4);
    int*    bsum  = (int*)alloc((size_t)NB * 4);
    int*    boff  = (int*)alloc((size_t)NB * 4);
    int2*   pack  = (int2*)alloc((size_t)EE * 8);         // 12.8 MB

    hipMemsetAsync(deg, 0, (size_t)NN * 4, stream);

    k_wt<<<(DIM * DIM + 255) / 256, 256, 0, stream>>>(W, mask, Wt);
    k_gemm<<<(NN + ROWS_PER_BLOCK - 1) / ROWS_PER_BLOCK, 256, 0, stream>>>(
        feat, Wt, attn, hh, sv);
    k_hist<<<1024, 256, 0, stream>>>(dst, deg);
    k_scan_a<<<NB, 256, 0, stream>>>(deg, offs, bsum);
    k_scan_b<<<1, 64, 0, stream>>>(bsum, boff);
    k_scan_c<<<(NN + 255) / 256, 256, 0, stream>>>(offs, boff, cursor);
    k_scatter<<<1024, 256, 0, stream>>>(src, dst, sv, cursor, pack);
    k_agg<<<(NN + 3) / 4, 256, 0, stream>>>(hh, offs, pack, out);
}

// Round 4
// 376.220 us; speedup vs baseline: 1.6530x; 1.2555x over previous
//
#include <hip/hip_runtime.h>
#include <math.h>

// Problem constants (fixed by the reference file)
#define NN 100000
#define EE 1600000
#define DIM 128
#define NB 98            // ceil(NN / 1024) scan blocks

typedef _Float16 half8 __attribute__((ext_vector_type(8)));
typedef _Float16 half2v __attribute__((ext_vector_type(2)));
typedef float f32x4 __attribute__((ext_vector_type(4)));

// ---------------------------------------------------------------------------
// Kernel 0: Bt[n*128+k] = W[n*128+k] * mask[k], cast fp16.
// This IS the MFMA B-operand layout (n = lane&15, k contiguous) — no transpose.
// ---------------------------------------------------------------------------
__global__ __launch_bounds__(256) void k_wt(const float* __restrict__ W,
                                            const float* __restrict__ mask,
                                            _Float16* __restrict__ Bt) {
    int o = blockIdx.x * 256 + threadIdx.x;
    if (o < DIM * DIM) Bt[o] = (_Float16)(W[o] * mask[o & 127]);
}

// ---------------------------------------------------------------------------
// Kernel 1: h = feat @ Bt^T via MFMA f32_16x16x32_f16, fp32 accumulate.
// One wave per 16-row M-tile (block = 4 waves = 64 rows). B (32 KB fp16) is
// L1/L2-resident; A loaded 32B/lane/K-chunk from fp32 feat, converted
// in-register. Epilogue: s = leaky_relu(h @ attn) from fp32 acc via 16-lane
// shuffle reduce; h stored fp16 for k_agg's gather.
// Fragment mappings (guide §3): A[m=lane&15][k=quad*8+j],
// B[k=quad*8+j][n=lane&15], C/D: col=lane&15, row=quad*4+reg.
// ---------------------------------------------------------------------------
__global__ __launch_bounds__(256) void k_gemm(const float* __restrict__ feat,
                                              const _Float16* __restrict__ Bt,
                                              const float* __restrict__ attn,
                                              _Float16* __restrict__ hh,
                                              float* __restrict__ s) {
    const int lane = threadIdx.x & 63;
    const int wv   = threadIdx.x >> 6;
    const int l15  = lane & 15;
    const int quad = lane >> 4;
    const int row0 = blockIdx.x * 64 + wv * 16;

    f32x4 acc[8];
#pragma unroll
    for (int nt = 0; nt < 8; ++nt) acc[nt] = (f32x4){0.f, 0.f, 0.f, 0.f};

    const int arow = row0 + l15;
    const bool okA = arow < NN;
    const float* ap = feat + (size_t)(okA ? arow : 0) * DIM + quad * 8;

#pragma unroll
    for (int kc = 0; kc < 4; ++kc) {
        half8 a;
        float4 f0 = ((const float4*)(ap + kc * 32))[0];
        float4 f1 = ((const float4*)(ap + kc * 32))[1];
        if (!okA) { f0 = make_float4(0, 0, 0, 0); f1 = make_float4(0, 0, 0, 0); }
        a[0] = (_Float16)f0.x; a[1] = (_Float16)f0.y;
        a[2] = (_Float16)f0.z; a[3] = (_Float16)f0.w;
        a[4] = (_Float16)f1.x; a[5] = (_Float16)f1.y;
        a[6] = (_Float16)f1.z; a[7] = (_Float16)f1.w;
#pragma unroll
        for (int nt = 0; nt < 8; ++nt) {
            half8 b = *(const half8*)(Bt + (size_t)(nt * 16 + l15) * DIM + kc * 32 + quad * 8);
            acc[nt] = __builtin_amdgcn_mfma_f32_16x16x32_f16(a, b, acc[nt], 0, 0, 0);
        }
    }

    float avv[8];
#pragma unroll
    for (int nt = 0; nt < 8; ++nt) avv[nt] = attn[nt * 16 + l15];

#pragma unroll
    for (int r = 0; r < 4; ++r) {
        int row = row0 + quad * 4 + r;
        float p = 0.f;
#pragma unroll
        for (int nt = 0; nt < 8; ++nt) p += acc[nt][r] * avv[nt];
        p += __shfl_xor(p, 1, 64);
        p += __shfl_xor(p, 2, 64);
        p += __shfl_xor(p, 4, 64);
        p += __shfl_xor(p, 8, 64);
        if (l15 == 0 && row < NN) s[row] = (p > 0.f) ? p : 0.01f * p;
    }

#pragma unroll
    for (int nt = 0; nt < 8; ++nt) {
#pragma unroll
        for (int r = 0; r < 4; ++r) {
            int row = row0 + quad * 4 + r;
            if (row < NN)
                hh[(size_t)row * DIM + nt * 16 + l15] = (_Float16)acc[nt][r];
        }
    }
}

// ---------------------------------------------------------------------------
// Kernel 2: histogram of dst -> deg[]
// ---------------------------------------------------------------------------
__global__ __launch_bounds__(256) void k_hist(const int* __restrict__ dst,
                                              int* __restrict__ deg) {
    for (int e = blockIdx.x * blockDim.x + threadIdx.x; e < EE;
         e += gridDim.x * blockDim.x)
        atomicAdd(&deg[dst[e]], 1);
}

// ---------------------------------------------------------------------------
// Kernels 3-5: exclusive scan of deg -> offs (CSR row pointers).
// ---------------------------------------------------------------------------
__global__ __launch_bounds__(256) void k_scan_a(const int* __restrict__ deg,
                                                int* __restrict__ excl,
                                                int* __restrict__ bsum) {
    __shared__ int wsum[4];
    __shared__ int woff[4];
    const int t = threadIdx.x, b = blockIdx.x;
    const int base = b * 1024 + t * 4;
    int v0 = (base + 0) < NN ? deg[base + 0] : 0;
    int v1 = (base + 1) < NN ? deg[base + 1] : 0;
    int v2 = (base + 2) < NN ? deg[base + 2] : 0;
    int v3 = (base + 3) < NN ? deg[base + 3] : 0;
    int tsum = v0 + v1 + v2 + v3;

    const int lane = t & 63, w = t >> 6;
    int incl = tsum;
#pragma unroll
    for (int d = 1; d < 64; d <<= 1) {
        int n = __shfl_up(incl, d, 64);
        if (lane >= d) incl += n;
    }
    if (lane == 63) wsum[w] = incl;
    __syncthreads();
    if (t == 0) {
        int run = 0;
#pragma unroll
        for (int i = 0; i < 4; ++i) { woff[i] = run; run += wsum[i]; }
        bsum[b] = run;
    }
    __syncthreads();
    int texcl = incl - tsum + woff[w];
    if (base + 0 < NN) excl[base + 0] = texcl;
    if (base + 1 < NN) excl[base + 1] = texcl + v0;
    if (base + 2 < NN) excl[base + 2] = texcl + v0 + v1;
    if (base + 3 < NN) excl[base + 3] = texcl + v0 + v1 + v2;
}

__global__ __launch_bounds__(64) void k_scan_b(const int* __restrict__ bsum,
                                               int* __restrict__ boff) {
    const int lane = threadIdx.x & 63;
    const int i0 = 2 * lane, i1 = 2 * lane + 1;
    int v0 = (i0 < NB) ? bsum[i0] : 0;
    int v1 = (i1 < NB) ? bsum[i1] : 0;
    int t = v0 + v1;
    int incl = t;
#pragma unroll
    for (int d = 1; d < 64; d <<= 1) {
        int n = __shfl_up(incl, d, 64);
        if (lane >= d) incl += n;
    }
    int excl = incl - t;
    if (i0 < NB) boff[i0] = excl;
    if (i1 < NB) boff[i1] = excl + v0;
}

__global__ __launch_bounds__(256) void k_scan_c(int* __restrict__ offs,
                                                const int* __restrict__ boff,
                                                int* __restrict__ cursor) {
    int i = blockIdx.x * 256 + threadIdx.x;
    if (i < NN) {
        int v = offs[i] + boff[i >> 10];
        offs[i] = v;
        cursor[i] = v;
    }
    if (i == 0) offs[NN] = EE;
}

// ---------------------------------------------------------------------------
// Kernel 6: scatter edges into CSR order; pack (src_idx, s[src]) as int2.
// ---------------------------------------------------------------------------
__global__ __launch_bounds__(256) void k_scatter(const int* __restrict__ src,
                                                 const int* __restrict__ dst,
                                                 const float* __restrict__ s,
                                                 int* __restrict__ cursor,
                                                 int2* __restrict__ pack) {
    for (int e = blockIdx.x * blockDim.x + threadIdx.x; e < EE;
         e += gridDim.x * blockDim.x) {
        int d  = dst[e];
        int si = src[e];
        float x = s[si];
        int pos = atomicAdd(&cursor[d], 1);
        pack[pos] = make_int2(si, __float_as_int(x));
    }
}

// ---------------------------------------------------------------------------
// Kernel 7: one wave per dst node; max pass + unrolled weighted accumulation.
// ---------------------------------------------------------------------------
__global__ __launch_bounds__(256) void k_agg(const _Float16* __restrict__ hh,
                                             const int* __restrict__ offs,
                                             const int2* __restrict__ pack,
                                             float* __restrict__ out) {
    const int wid  = blockIdx.x * 4 + (threadIdx.x >> 6);
    const int lane = threadIdx.x & 63;
    if (wid >= NN) return;
    const int beg = offs[wid], end = offs[wid + 1];

    float m = -INFINITY;
    for (int p = beg + lane; p < end; p += 64)
        m = fmaxf(m, __int_as_float(pack[p].y));
#pragma unroll
    for (int d = 1; d < 64; d <<= 1)
        m = fmaxf(m, __shfl_xor(m, d, 64));

    const half2v* h2 = (const half2v*)hh;
    float l = 0.f;
    float2 a0 = make_float2(0.f, 0.f), a1 = make_float2(0.f, 0.f);
    float2 a2 = make_float2(0.f, 0.f), a3 = make_float2(0.f, 0.f);
    int p = beg;
    for (; p + 3 < end; p += 4) {
        int2 e0 = pack[p], e1 = pack[p + 1], e2 = pack[p + 2], e3 = pack[p + 3];
        float w0 = __expf(__int_as_float(e0.y) - m);
        float w1 = __expf(__int_as_float(e1.y) - m);
        float w2 = __expf(__int_as_float(e2.y) - m);
        float w3 = __expf(__int_as_float(e3.y) - m);
        half2v v0 = h2[(size_t)e0.x * 64 + lane];
        half2v v1 = h2[(size_t)e1.x * 64 + lane];
        half2v v2 = h2[(size_t)e2.x * 64 + lane];
        half2v v3 = h2[(size_t)e3.x * 64 + lane];
        a0.x = fmaf((float)v0[0], w0, a0.x); a0.y = fmaf((float)v0[1], w0, a0.y);
        a1.x = fmaf((float)v1[0], w1, a1.x); a1.y = fmaf((float)v1[1], w1, a1.y);
        a2.x = fmaf((float)v2[0], w2, a2.x); a2.y = fmaf((float)v2[1], w2, a2.y);
        a3.x = fmaf((float)v3[0], w3, a3.x); a3.y = fmaf((float)v3[1], w3, a3.y);
        l += (w0 + w1) + (w2 + w3);
    }
    for (; p < end; ++p) {
        int2 e0 = pack[p];
        float w0 = __expf(__int_as_float(e0.y) - m);
        half2v v0 = h2[(size_t)e0.x * 64 + lane];
        a0.x = fmaf((float)v0[0], w0, a0.x); a0.y = fmaf((float)v0[1], w0, a0.y);
        l += w0;
    }

    float inv = (l > 0.f) ? (1.0f / l) : 0.f;
    float rx = fmaxf((a0.x + a1.x + a2.x + a3.x) * inv, 0.f);
    float ry = fmaxf((a0.y + a1.y + a2.y + a3.y) * inv, 0.f);
    ((float2*)out)[(size_t)wid * 64 + lane] = make_float2(rx, ry);
}

// ---------------------------------------------------------------------------
extern "C" void kernel_launch(void* const* d_in, const int* in_sizes, int n_in,
                              void* d_out, int out_size, void* d_ws, size_t ws_size,
                              hipStream_t stream) {
    const float* feat = (const float*)d_in[0];
    const float* mask = (const float*)d_in[1];
    const float* W    = (const float*)d_in[2];
    const float* attn = (const float*)d_in[3];
    const int*   src  = (const int*)d_in[4];
    const int*   dst  = (const int*)d_in[5];
    float* out = (float*)d_out;

    // Workspace carve-up (~40 MB total)
    char* ws = (char*)d_ws;
    size_t off = 0;
    auto alloc = [&](size_t bytes) -> void* {
        void* p = ws + off;
        off = (off + bytes + 511) & ~(size_t)511;
        return p;
    };
    _Float16* hh  = (_Float16*)alloc((size_t)NN * DIM * 2); // 25.6 MB
    float*  sv    = (float*)alloc((size_t)NN * 4);
    _Float16* Bt  = (_Float16*)alloc((size_t)DIM * DIM * 2);
    int*    deg   = (int*)alloc((size_t)NN * 4);
    int*    offs  = (int*)alloc((size_t)(NN + 1) * 4);
    int*    cursor= (int*)alloc((size_t)NN * 4);
    int*    bsum  = (int*)alloc((size_t)NB * 4);
    int*    boff  = (int*)alloc((size_t)NB * 4);
    int2*   pack  = (int2*)alloc((size_t)EE * 8);           // 12.8 MB

    (void)hipMemsetAsync(deg, 0, (size_t)NN * 4, stream);

    k_wt<<<(DIM * DIM + 255) / 256, 256, 0, stream>>>(W, mask, Bt);
    k_gemm<<<(NN + 63) / 64, 256, 0, stream>>>(feat, Bt, attn, hh, sv);
    k_hist<<<1024, 256, 0, stream>>>(dst, deg);
    k_scan_a<<<NB, 256, 0, stream>>>(deg, offs, bsum);
    k_scan_b<<<1, 64, 0, stream>>>(bsum, boff);
    k_scan_c<<<(NN + 255) / 256, 256, 0, stream>>>(offs, boff, cursor);
    k_scatter<<<1024, 256, 0, stream>>>(src, dst, sv, cursor, pack);
    k_agg<<<(NN + 3) / 4, 256, 0, stream>>>(hh, offs, pack, out);
}